// Round 4
// baseline (318.788 us; speedup 1.0000x reference)
//
#include <hip/hip_runtime.h>

#define TPB 256
#define N_RELS 64

__device__ __forceinline__ void edge_compute(
    const float* __restrict__ sM, const float* __restrict__ sB,
    int r, float p0, float p1, float p2,
    float c0, float c1, float c2,
    float zeps, float sf, float* __restrict__ o)
{
    const float* m = &sM[r * 9];
    const float* b = &sB[r * 3];

    // scores = M[r] @ c
    float s0 = m[0] * c0 + m[1] * c1 + m[2] * c2;
    float s1 = m[3] * c0 + m[4] * c1 + m[5] * c2;
    float s2 = m[6] * c0 + m[7] * c1 + m[8] * c2;

    // softmax (max-subtracted)
    float mx = fmaxf(fmaxf(s0, s1), s2);
    float e0 = __expf(s0 - mx);
    float e1 = __expf(s1 - mx);
    float e2 = __expf(s2 - mx);
    float inv = __fdividef(1.0f, e0 + e1 + e2);
    float ch0 = e0 * inv, ch1 = e1 * inv, ch2 = e2 * inv;

    // alpha = (1-b)*p + b*ch  =  p + b*(ch-p)
    float b0 = b[0], b1 = b[1], b2 = b[2];
    float a0 = p0 + b0 * (ch0 - p0);
    float a1 = p1 + b1 * (ch1 - p1);
    float a2 = p2 + b2 * (ch2 - p2);

    // ---- scale(p, ch) ----
    // entropy of clipped renormalized blend
    float z0 = fmaxf(zeps, p0 + ch0);
    float z1 = fmaxf(zeps, p1 + ch1);
    float z2 = fmaxf(zeps, p2 + ch2);
    float zinv = __fdividef(1.0f, z0 + z1 + z2);
    float zn0 = z0 * zinv, zn1 = z1 * zinv, zn2 = z2 * zinv;
    float ent = -(zn0 * __logf(zn0) + zn1 * __logf(zn1) + zn2 * __logf(zn2));

    // cosine similarity
    float dot = p0 * ch0 + p1 * ch1 + p2 * ch2;
    float np2 = p0 * p0 + p1 * p1 + p2 * p2;
    float nc2 = ch0 * ch0 + ch1 * ch1 + ch2 * ch2;
    float prod = np2 * nc2;
    float cosn = (prod > 0.0f) ? dot * rsqrtf(prod) : dot;  // norm==0 -> divide by 1
    float cosv = 1.1f + cosn;

    float scale = sf * cosv * __fdividef(1.0f, ent);

    o[0] = a0 * scale;
    o[1] = a1 * scale;
    o[2] = a2 * scale;
}

__global__ __launch_bounds__(TPB) void alpha_kernel(
    const float* __restrict__ prnt,
    const float* __restrict__ child,
    const int*   __restrict__ rels,
    const float* __restrict__ M,
    const float* __restrict__ beta,
    const float* __restrict__ zeps_p,
    const float* __restrict__ sf_p,
    float* __restrict__ out,
    int n_groups,   // full groups of 4 edges
    int n_edges)
{
    __shared__ float sM[N_RELS * 9];
    __shared__ float sB[N_RELS * 3];
    for (int i = threadIdx.x; i < N_RELS * 9; i += TPB) sM[i] = M[i];
    for (int i = threadIdx.x; i < N_RELS * 3; i += TPB) sB[i] = beta[i];
    __syncthreads();

    const float zeps = *zeps_p;
    const float sf   = *sf_p;

    int g = blockIdx.x * TPB + threadIdx.x;

    if (g < n_groups) {
        const float4* p4 = (const float4*)prnt;
        const float4* c4 = (const float4*)child;
        const int4*   r4 = (const int4*)rels;

        float4 pa = p4[g * 3 + 0], pb = p4[g * 3 + 1], pc = p4[g * 3 + 2];
        float4 ca = c4[g * 3 + 0], cb = c4[g * 3 + 1], cc = c4[g * 3 + 2];
        int4   rr = r4[g];

        float P[4][3] = {{pa.x, pa.y, pa.z}, {pa.w, pb.x, pb.y},
                         {pb.z, pb.w, pc.x}, {pc.y, pc.z, pc.w}};
        float C[4][3] = {{ca.x, ca.y, ca.z}, {ca.w, cb.x, cb.y},
                         {cb.z, cb.w, cc.x}, {cc.y, cc.z, cc.w}};
        int   R[4]    = {rr.x, rr.y, rr.z, rr.w};

        float O[4][3];
        #pragma unroll
        for (int e = 0; e < 4; ++e) {
            edge_compute(sM, sB, R[e],
                         P[e][0], P[e][1], P[e][2],
                         C[e][0], C[e][1], C[e][2],
                         zeps, sf, O[e]);
        }

        float4* o4 = (float4*)out;
        o4[g * 3 + 0] = make_float4(O[0][0], O[0][1], O[0][2], O[1][0]);
        o4[g * 3 + 1] = make_float4(O[1][1], O[1][2], O[2][0], O[2][1]);
        o4[g * 3 + 2] = make_float4(O[2][2], O[3][0], O[3][1], O[3][2]);
    } else {
        // scalar tail (only when n_edges % 4 != 0)
        int t = g - n_groups;
        int eidx = n_groups * 4 + t;
        if (t >= 0 && eidx < n_edges) {
            float o[3];
            edge_compute(sM, sB, rels[eidx],
                         prnt[eidx * 3 + 0], prnt[eidx * 3 + 1], prnt[eidx * 3 + 2],
                         child[eidx * 3 + 0], child[eidx * 3 + 1], child[eidx * 3 + 2],
                         zeps, sf, o);
            out[eidx * 3 + 0] = o[0];
            out[eidx * 3 + 1] = o[1];
            out[eidx * 3 + 2] = o[2];
        }
    }
}

extern "C" void kernel_launch(void* const* d_in, const int* in_sizes, int n_in,
                              void* d_out, int out_size, void* d_ws, size_t ws_size,
                              hipStream_t stream) {
    // input order: var_sfx, prnt_probs, child_probs, rels, M, beta, z_epsilon, scale_factor
    const float* prnt  = (const float*)d_in[1];
    const float* child = (const float*)d_in[2];
    const int*   rels  = (const int*)d_in[3];
    const float* M     = (const float*)d_in[4];
    const float* beta  = (const float*)d_in[5];
    const float* zeps  = (const float*)d_in[6];
    const float* sf    = (const float*)d_in[7];
    float* out = (float*)d_out;

    int n_edges  = in_sizes[3];        // rels is [E]
    int n_groups = n_edges / 4;        // full groups of 4
    int tail     = n_edges - n_groups * 4;
    int work     = n_groups + tail;    // tail threads appended after groups
    int blocks   = (work + TPB - 1) / TPB;

    alpha_kernel<<<blocks, TPB, 0, stream>>>(prnt, child, rels, M, beta,
                                             zeps, sf, out, n_groups, n_edges);
}